// Round 4
// baseline (804.142 us; speedup 1.0000x reference)
//
#include <hip/hip_runtime.h>

#define EE 600000
#define NN 50000
#define DD 128

typedef __bf16 bf16x8 __attribute__((ext_vector_type(8)));
typedef float f32x4 __attribute__((ext_vector_type(4)));
typedef unsigned short u16x8 __attribute__((ext_vector_type(8)));

__device__ inline unsigned short f2bf(float f) {
  unsigned int u = __builtin_bit_cast(unsigned int, f);
  u += 0x7FFFu + ((u >> 16) & 1u);
  return (unsigned short)(u >> 16);
}

__device__ inline float softplus_f(float v) {
  // log1p(exp(v)) stable: max(v,0) + log(1+exp(-|v|))
  return fmaxf(v, 0.0f) + __logf(1.0f + __expf(-fabsf(v)));
}

// ---------------- prep: x->bf16, weights -> MFMA B-frag layout, aggr zero ----------------
// Wf[kt][nt][lane][j] = bf16( W[kt*32 + (lane>>4)*8 + j][nt*16 + (lane&15)] )
__global__ void prep_kernel(const float* __restrict__ x,
                            const float* __restrict__ W1, const float* __restrict__ W2,
                            const float* __restrict__ Wn,
                            unsigned short* __restrict__ xbf, unsigned short* __restrict__ w1f,
                            unsigned short* __restrict__ w2f, unsigned short* __restrict__ wnf,
                            float* __restrict__ aggr) {
  const int id = blockIdx.x * 256 + threadIdx.x;
  if (id < 800000) {                       // x: 6.4M f32 -> bf16, 8 per thread
    const f32x4* src = (const f32x4*)(x + (size_t)id * 8);
    f32x4 f0 = src[0], f1 = src[1];
    u16x8 v;
#pragma unroll
    for (int j = 0; j < 4; ++j) { v[j] = f2bf(f0[j]); v[4 + j] = f2bf(f1[j]); }
    *(u16x8*)(xbf + (size_t)id * 8) = v;
  } else if (id < 812288) {                // W1f: 12 kt x 16 nt x 64 lanes
    const int u = id - 800000;
    const int l = u & 63, t2 = u >> 6, nt = t2 & 15, kt = t2 >> 4;
    const int n = nt * 16 + (l & 15);
    const int kb = kt * 32 + ((l >> 4) << 3);
    u16x8 v;
#pragma unroll
    for (int j = 0; j < 8; ++j) v[j] = f2bf(W1[(size_t)(kb + j) * 256 + n]);
    *(u16x8*)(w1f + (size_t)u * 8) = v;
  } else if (id < 816384) {                // W2f: 8 kt x 8 nt x 64 lanes
    const int u = id - 812288;
    const int l = u & 63, t2 = u >> 6, nt = t2 & 7, kt = t2 >> 3;
    const int n = nt * 16 + (l & 15);
    const int kb = kt * 32 + ((l >> 4) << 3);
    u16x8 v;
#pragma unroll
    for (int j = 0; j < 8; ++j) v[j] = f2bf(W2[(size_t)(kb + j) * 128 + n]);
    *(u16x8*)(w2f + (size_t)u * 8) = v;
  } else if (id < 820480) {                // Wnf: 8 kt x 8 nt x 64 lanes
    const int u = id - 816384;
    const int l = u & 63, t2 = u >> 6, nt = t2 & 7, kt = t2 >> 3;
    const int n = nt * 16 + (l & 15);
    const int kb = kt * 32 + ((l >> 4) << 3);
    u16x8 v;
#pragma unroll
    for (int j = 0; j < 8; ++j) v[j] = f2bf(Wn[(size_t)(kb + j) * 128 + n]);
    *(u16x8*)(wnf + (size_t)u * 8) = v;
  } else if (id < 2420480) {               // aggr zero-fill: 1.6M threads x f32x4
    const int u = id - 820480;
    *(f32x4*)(aggr + (size_t)u * 4) = f32x4{0.f, 0.f, 0.f, 0.f};
  }
}

// ---------------- edge MLP + scatter ----------------
// 32 edges/block, 4 waves: wave w owns cols [w*64,w*64+64) in L1, [w*32,w*32+32) in L2.
// LDS 24.7KB -> 6 blocks/CU (24 waves, 75% occupancy) for latency hiding.
__global__ __launch_bounds__(256, 6) void edge_kernel(
    const int* __restrict__ ei, const float* __restrict__ eattr,
    const float* __restrict__ b1, const float* __restrict__ b2,
    const unsigned short* __restrict__ xbf,
    const unsigned short* __restrict__ w1f, const unsigned short* __restrict__ w2f,
    float* __restrict__ aggr) {
  __shared__ __align__(16) unsigned short At[12288];  // 32 x 384 bf16 = 24KB (reused as H 32x256)
  __shared__ int colS[32];
  const int t = threadIdx.x;
  const int lane = t & 63;
  const int w = t >> 6;
  const int base = blockIdx.x * 32;

  // ---- stage A = [x[row] | x[col] | edge_attr] as bf16, XOR-swizzled ----
  {
    const int r = t >> 3, p = t & 7;            // 8 threads per edge-row
    const int e = base + r;
    const int sr = ei[e], sc = ei[EE + e];
    if (p == 0) colS[r] = sc;
    const u16x8* xr = (const u16x8*)(xbf + (size_t)sr * DD);
    const u16x8* xc = (const u16x8*)(xbf + (size_t)sc * DD);
    const f32x4* ea = (const f32x4*)(eattr + (size_t)e * DD);
    const int swz = (r & 7) << 4;
    unsigned short* rowp = At + r * 384;        // 768B pitch
#pragma unroll
    for (int i = 0; i < 2; ++i) {
      const int c = 2 * p + i;                  // u16x8 chunk 0..15
      const int cb = c * 16;                    // byte col
      *(u16x8*)(rowp + ((cb ^ swz) >> 1)) = xr[c];
      *(u16x8*)(rowp + (((256 + cb) ^ swz) >> 1)) = xc[c];
      f32x4 f0 = ea[2 * c], f1 = ea[2 * c + 1];
      u16x8 v;
#pragma unroll
      for (int j = 0; j < 4; ++j) { v[j] = f2bf(f0[j]); v[4 + j] = f2bf(f1[j]); }
      *(u16x8*)(rowp + (((512 + cb) ^ swz) >> 1)) = v;
    }
  }
  __syncthreads();

  const int lr = lane & 15;
  const int lkb = (lane >> 4) << 4;  // byte offset of k-chunk within 64B k-tile

  // ---- layer 1: C1[32][256] = A @ W1 ----
  f32x4 acc[2][4] = {};
#pragma unroll
  for (int kt = 0; kt < 12; ++kt) {
    bf16x8 a[2];
#pragma unroll
    for (int mt = 0; mt < 2; ++mt) {
      const int row = mt * 16 + lr;
      const int cb = kt * 64 + lkb;
      a[mt] = __builtin_bit_cast(bf16x8,
              *(const u16x8*)(At + ((row * 768 + (cb ^ ((row & 7) << 4))) >> 1)));
    }
#pragma unroll
    for (int nt = 0; nt < 4; ++nt) {
      const u16x8 bv = *(const u16x8*)(w1f + ((size_t)((kt * 16 + (w * 4 + nt)) * 64 + lane) << 3));
      const bf16x8 b = __builtin_bit_cast(bf16x8, bv);
#pragma unroll
      for (int mt = 0; mt < 2; ++mt)
        acc[mt][nt] = __builtin_amdgcn_mfma_f32_16x16x32_bf16(a[mt], b, acc[mt][nt], 0, 0, 0);
    }
  }
  __syncthreads();  // everyone done reading A before H overwrites it

  // ---- H = softplus(C1+b1) -> bf16 into LDS (32 x 256, pitch 512B, swizzled) ----
#pragma unroll
  for (int nt = 0; nt < 4; ++nt) {
    const int col = w * 64 + nt * 16 + lr;
    const float bias = b1[col];
#pragma unroll
    for (int mt = 0; mt < 2; ++mt) {
#pragma unroll
      for (int reg = 0; reg < 4; ++reg) {
        const int row = mt * 16 + ((lane >> 4) << 2) + reg;
        const float hv = softplus_f(acc[mt][nt][reg] + bias);
        At[(row * 512 + ((col * 2) ^ ((row & 7) << 4))) >> 1] = f2bf(hv);
      }
    }
  }
  __syncthreads();

  // ---- layer 2: C2[32][128] = H @ W2 ----
  f32x4 acc2[2][2] = {};
#pragma unroll
  for (int kt = 0; kt < 8; ++kt) {
    bf16x8 a[2];
#pragma unroll
    for (int mt = 0; mt < 2; ++mt) {
      const int row = mt * 16 + lr;
      const int cb = kt * 64 + lkb;
      a[mt] = __builtin_bit_cast(bf16x8,
              *(const u16x8*)(At + ((row * 512 + (cb ^ ((row & 7) << 4))) >> 1)));
    }
#pragma unroll
    for (int nt = 0; nt < 2; ++nt) {
      const u16x8 bv = *(const u16x8*)(w2f + ((size_t)((kt * 8 + (w * 2 + nt)) * 64 + lane) << 3));
      const bf16x8 b = __builtin_bit_cast(bf16x8, bv);
#pragma unroll
      for (int mt = 0; mt < 2; ++mt)
        acc2[mt][nt] = __builtin_amdgcn_mfma_f32_16x16x32_bf16(a[mt], b, acc2[mt][nt], 0, 0, 0);
    }
  }

  // ---- epilogue: softplus + atomic scatter-add to aggr[col[e]] ----
#pragma unroll
  for (int nt = 0; nt < 2; ++nt) {
    const int col = w * 32 + nt * 16 + lr;
    const float bias = b2[col];
#pragma unroll
    for (int mt = 0; mt < 2; ++mt) {
#pragma unroll
      for (int reg = 0; reg < 4; ++reg) {
        const int row = mt * 16 + ((lane >> 4) << 2) + reg;
        const float v = softplus_f(acc2[mt][nt][reg] + bias);
        float* p = aggr + (size_t)colS[row] * DD + col;
        __hip_atomic_fetch_add(p, v, __ATOMIC_RELAXED, __HIP_MEMORY_SCOPE_AGENT);
      }
    }
  }
}

// ---------------- node MLP + residual ----------------
__global__ __launch_bounds__(256, 4) void node_kernel(
    const float* __restrict__ x, const float* __restrict__ bn,
    const unsigned short* __restrict__ xbf, const unsigned short* __restrict__ wnf,
    const float* __restrict__ aggr, float* __restrict__ out) {
  __shared__ __align__(16) unsigned short At[16384];  // 64 x 256 bf16 = 32KB
  const int t = threadIdx.x;
  const int lane = t & 63;
  const int w = t >> 6;
  const int base = blockIdx.x * 64;

  {
    const int r = t >> 2, p = t & 3;
    const int node = base + r;
    const int swz = (r & 7) << 4;
    unsigned short* rowp = At + ((r * 512) >> 1);
    if (node < NN) {
      const u16x8* xr = (const u16x8*)(xbf + (size_t)node * DD + p * 32);
      const f32x4* ag = (const f32x4*)(aggr + (size_t)node * DD + p * 32);
#pragma unroll
      for (int i = 0; i < 4; ++i) {
        const int c2 = (p * 32 + i * 8) * 2;
        *(u16x8*)(rowp + ((c2 ^ swz) >> 1)) = xr[i];
        f32x4 f0 = ag[2 * i], f1 = ag[2 * i + 1];
        u16x8 v;
#pragma unroll
        for (int j = 0; j < 4; ++j) { v[j] = f2bf(f0[j]); v[4 + j] = f2bf(f1[j]); }
        *(u16x8*)(rowp + (((256 + c2) ^ swz) >> 1)) = v;
      }
    } else {
      const u16x8 z = {};
#pragma unroll
      for (int i = 0; i < 4; ++i) {
        const int c2 = (p * 32 + i * 8) * 2;
        *(u16x8*)(rowp + ((c2 ^ swz) >> 1)) = z;
        *(u16x8*)(rowp + (((256 + c2) ^ swz) >> 1)) = z;
      }
    }
  }
  __syncthreads();

  const int lr = lane & 15;
  const int lkb = (lane >> 4) << 4;
  f32x4 acc[4][2] = {};
#pragma unroll
  for (int kt = 0; kt < 8; ++kt) {
    bf16x8 a[4];
#pragma unroll
    for (int mt = 0; mt < 4; ++mt) {
      const int row = mt * 16 + lr;
      const int cb = kt * 64 + lkb;
      a[mt] = __builtin_bit_cast(bf16x8,
              *(const u16x8*)(At + ((row * 512 + (cb ^ ((row & 7) << 4))) >> 1)));
    }
#pragma unroll
    for (int nt = 0; nt < 2; ++nt) {
      const u16x8 bv = *(const u16x8*)(wnf + ((size_t)((kt * 8 + (w * 2 + nt)) * 64 + lane) << 3));
      const bf16x8 b = __builtin_bit_cast(bf16x8, bv);
#pragma unroll
      for (int mt = 0; mt < 4; ++mt)
        acc[mt][nt] = __builtin_amdgcn_mfma_f32_16x16x32_bf16(a[mt], b, acc[mt][nt], 0, 0, 0);
    }
  }

#pragma unroll
  for (int nt = 0; nt < 2; ++nt) {
    const int col = w * 32 + nt * 16 + lr;
    const float bias = bn[col];
#pragma unroll
    for (int mt = 0; mt < 4; ++mt) {
#pragma unroll
      for (int reg = 0; reg < 4; ++reg) {
        const int row = mt * 16 + ((lane >> 4) << 2) + reg;
        const int node = base + row;
        if (node < NN) {
          const size_t o = (size_t)node * DD + col;
          out[o] = softplus_f(acc[mt][nt][reg] + bias) + x[o];
        }
      }
    }
  }
}

// ---------------- launch ----------------
extern "C" void kernel_launch(void* const* d_in, const int* in_sizes, int n_in,
                              void* d_out, int out_size, void* d_ws, size_t ws_size,
                              hipStream_t stream) {
  const float* x = (const float*)d_in[0];
  const int* ei = (const int*)d_in[1];
  const float* eattr = (const float*)d_in[2];
  const float* W1 = (const float*)d_in[3];
  const float* b1 = (const float*)d_in[4];
  const float* W2 = (const float*)d_in[5];
  const float* b2 = (const float*)d_in[6];
  const float* Wn = (const float*)d_in[7];
  const float* bn = (const float*)d_in[8];
  float* out = (float*)d_out;

  char* ws = (char*)d_ws;
  float* aggr = (float*)(ws);                                // 25,600,000 B
  unsigned short* xbf = (unsigned short*)(ws + 25600000);    // 12,800,000 B
  unsigned short* w1f = (unsigned short*)(ws + 38400000);    //    196,608 B
  unsigned short* w2f = (unsigned short*)(ws + 38596608);    //     65,536 B
  unsigned short* wnf = (unsigned short*)(ws + 38662144);    //     65,536 B  (end 38,727,680)

  prep_kernel<<<9455, 256, 0, stream>>>(x, W1, W2, Wn, xbf, w1f, w2f, wnf, aggr);
  edge_kernel<<<18750, 256, 0, stream>>>(ei, eattr, b1, b2, xbf, w1f, w2f, aggr);
  node_kernel<<<782, 256, 0, stream>>>(x, bn, xbf, wnf, aggr, out);
}

// Round 5
// 756.753 us; speedup vs baseline: 1.0626x; 1.0626x over previous
//
#include <hip/hip_runtime.h>

#define EE 600000
#define NN 50000
#define DD 128

// fixed-point scale for aggr accumulation (values positive, sum < 2^9 -> 2^31/2^22)
#define FXS 4194304.0f            // 2^22
#define FXI 2.3841858e-07f        // 2^-22

typedef __bf16 bf16x8 __attribute__((ext_vector_type(8)));
typedef float f32x4 __attribute__((ext_vector_type(4)));
typedef unsigned short u16x8 __attribute__((ext_vector_type(8)));

__device__ inline unsigned short f2bf(float f) {
  unsigned int u = __builtin_bit_cast(unsigned int, f);
  u += 0x7FFFu + ((u >> 16) & 1u);
  return (unsigned short)(u >> 16);
}

__device__ inline float softplus_f(float v) {
  // log1p(exp(v)) stable: max(v,0) + log(1+exp(-|v|))
  return fmaxf(v, 0.0f) + __logf(1.0f + __expf(-fabsf(v)));
}

// ---------------- prep: x->bf16, weights -> MFMA B-frag layout, aggr zero ----------------
// Wf[kt][nt][lane][j] = bf16( W[kt*32 + (lane>>4)*8 + j][nt*16 + (lane&15)] )
__global__ void prep_kernel(const float* __restrict__ x,
                            const float* __restrict__ W1, const float* __restrict__ W2,
                            const float* __restrict__ Wn,
                            unsigned short* __restrict__ xbf, unsigned short* __restrict__ w1f,
                            unsigned short* __restrict__ w2f, unsigned short* __restrict__ wnf,
                            float* __restrict__ aggr) {
  const int id = blockIdx.x * 256 + threadIdx.x;
  if (id < 800000) {                       // x: 6.4M f32 -> bf16, 8 per thread
    const f32x4* src = (const f32x4*)(x + (size_t)id * 8);
    f32x4 f0 = src[0], f1 = src[1];
    u16x8 v;
#pragma unroll
    for (int j = 0; j < 4; ++j) { v[j] = f2bf(f0[j]); v[4 + j] = f2bf(f1[j]); }
    *(u16x8*)(xbf + (size_t)id * 8) = v;
  } else if (id < 812288) {                // W1f: 12 kt x 16 nt x 64 lanes
    const int u = id - 800000;
    const int l = u & 63, t2 = u >> 6, nt = t2 & 15, kt = t2 >> 4;
    const int n = nt * 16 + (l & 15);
    const int kb = kt * 32 + ((l >> 4) << 3);
    u16x8 v;
#pragma unroll
    for (int j = 0; j < 8; ++j) v[j] = f2bf(W1[(size_t)(kb + j) * 256 + n]);
    *(u16x8*)(w1f + (size_t)u * 8) = v;
  } else if (id < 816384) {                // W2f: 8 kt x 8 nt x 64 lanes
    const int u = id - 812288;
    const int l = u & 63, t2 = u >> 6, nt = t2 & 7, kt = t2 >> 3;
    const int n = nt * 16 + (l & 15);
    const int kb = kt * 32 + ((l >> 4) << 3);
    u16x8 v;
#pragma unroll
    for (int j = 0; j < 8; ++j) v[j] = f2bf(W2[(size_t)(kb + j) * 128 + n]);
    *(u16x8*)(w2f + (size_t)u * 8) = v;
  } else if (id < 820480) {                // Wnf: 8 kt x 8 nt x 64 lanes
    const int u = id - 816384;
    const int l = u & 63, t2 = u >> 6, nt = t2 & 7, kt = t2 >> 3;
    const int n = nt * 16 + (l & 15);
    const int kb = kt * 32 + ((l >> 4) << 3);
    u16x8 v;
#pragma unroll
    for (int j = 0; j < 8; ++j) v[j] = f2bf(Wn[(size_t)(kb + j) * 128 + n]);
    *(u16x8*)(wnf + (size_t)u * 8) = v;
  } else if (id < 2420480) {               // aggr zero-fill (25.6MB, bitwise zero = fx zero)
    const int u = id - 820480;
    *(f32x4*)(aggr + (size_t)u * 4) = f32x4{0.f, 0.f, 0.f, 0.f};
  }
}

// ---------------- edge MLP + scatter ----------------
// 64 edges/block (round-2 config: best WRITE/FETCH profile), 4 waves.
// Epilogue: u32 fixed-point, adjacent-col pair packed into one u64 atomic (halves atomic count).
__global__ __launch_bounds__(256, 3) void edge_kernel(
    const int* __restrict__ ei, const float* __restrict__ eattr,
    const float* __restrict__ b1, const float* __restrict__ b2,
    const unsigned short* __restrict__ xbf,
    const unsigned short* __restrict__ w1f, const unsigned short* __restrict__ w2f,
    unsigned long long* __restrict__ aggr64) {
  __shared__ __align__(16) unsigned short At[24576];  // 64 x 384 bf16 = 48KB (reused as H 64x256)
  __shared__ int colS[64];
  const int t = threadIdx.x;
  const int lane = t & 63;
  const int w = t >> 6;
  const int base = blockIdx.x * 64;

  // ---- stage A = [x[row] | x[col] | edge_attr] as bf16, XOR-swizzled ----
  {
    const int r = t >> 2, p = t & 3;
    const int e = base + r;
    const int sr = ei[e], sc = ei[EE + e];
    if (p == 0) colS[r] = sc;
    const u16x8* xr = (const u16x8*)(xbf + (size_t)sr * DD + p * 32);
    const u16x8* xc = (const u16x8*)(xbf + (size_t)sc * DD + p * 32);
    const f32x4* ea = (const f32x4*)(eattr + (size_t)e * DD + p * 32);
    const int swz = (r & 7) << 4;
    unsigned short* rowp = At + ((r * 768) >> 1);
#pragma unroll
    for (int i = 0; i < 4; ++i) {
      const int c2 = (p * 32 + i * 8) * 2;  // byte col
      *(u16x8*)(rowp + ((c2 ^ swz) >> 1)) = xr[i];
      *(u16x8*)(rowp + (((256 + c2) ^ swz) >> 1)) = xc[i];
      f32x4 f0 = ea[2 * i], f1 = ea[2 * i + 1];
      u16x8 v;
#pragma unroll
      for (int j = 0; j < 4; ++j) { v[j] = f2bf(f0[j]); v[4 + j] = f2bf(f1[j]); }
      *(u16x8*)(rowp + (((512 + c2) ^ swz) >> 1)) = v;
    }
  }
  __syncthreads();

  const int lr = lane & 15;
  const int lkb = (lane >> 4) << 4;  // byte offset of k-chunk within 64B k-tile

  // ---- layer 1: C1[64][256] = A @ W1 ----
  f32x4 acc[4][4] = {};
#pragma unroll
  for (int kt = 0; kt < 12; ++kt) {
    bf16x8 a[4];
#pragma unroll
    for (int mt = 0; mt < 4; ++mt) {
      const int row = mt * 16 + lr;
      const int cb = kt * 64 + lkb;
      a[mt] = __builtin_bit_cast(bf16x8,
              *(const u16x8*)(At + ((row * 768 + (cb ^ ((row & 7) << 4))) >> 1)));
    }
#pragma unroll
    for (int nt = 0; nt < 4; ++nt) {
      const u16x8 bv = *(const u16x8*)(w1f + ((size_t)((kt * 16 + (w * 4 + nt)) * 64 + lane) << 3));
      const bf16x8 b = __builtin_bit_cast(bf16x8, bv);
#pragma unroll
      for (int mt = 0; mt < 4; ++mt)
        acc[mt][nt] = __builtin_amdgcn_mfma_f32_16x16x32_bf16(a[mt], b, acc[mt][nt], 0, 0, 0);
    }
  }
  __syncthreads();  // everyone done reading A before H overwrites it

  // ---- H = softplus(C1+b1) -> bf16 into LDS (64 x 256, pitch 512B, swizzled) ----
#pragma unroll
  for (int nt = 0; nt < 4; ++nt) {
    const int col = w * 64 + nt * 16 + lr;
    const float bias = b1[col];
#pragma unroll
    for (int mt = 0; mt < 4; ++mt) {
#pragma unroll
      for (int reg = 0; reg < 4; ++reg) {
        const int row = mt * 16 + ((lane >> 4) << 2) + reg;
        const float hv = softplus_f(acc[mt][nt][reg] + bias);
        At[(row * 512 + ((col * 2) ^ ((row & 7) << 4))) >> 1] = f2bf(hv);
      }
    }
  }
  __syncthreads();

  // ---- layer 2: C2[64][128] = H @ W2 ----
  f32x4 acc2[4][2] = {};
#pragma unroll
  for (int kt = 0; kt < 8; ++kt) {
    bf16x8 a[4];
#pragma unroll
    for (int mt = 0; mt < 4; ++mt) {
      const int row = mt * 16 + lr;
      const int cb = kt * 64 + lkb;
      a[mt] = __builtin_bit_cast(bf16x8,
              *(const u16x8*)(At + ((row * 512 + (cb ^ ((row & 7) << 4))) >> 1)));
    }
#pragma unroll
    for (int nt = 0; nt < 2; ++nt) {
      const u16x8 bv = *(const u16x8*)(w2f + ((size_t)((kt * 8 + (w * 2 + nt)) * 64 + lane) << 3));
      const bf16x8 b = __builtin_bit_cast(bf16x8, bv);
#pragma unroll
      for (int mt = 0; mt < 4; ++mt)
        acc2[mt][nt] = __builtin_amdgcn_mfma_f32_16x16x32_bf16(a[mt], b, acc2[mt][nt], 0, 0, 0);
    }
  }

  // ---- epilogue: softplus -> u32 fixed point; pack col-pair via shfl_xor(1); u64 atomic ----
  const int parity = lane & 1;             // == col & 1
#pragma unroll
  for (int nt = 0; nt < 2; ++nt) {
    const int col = w * 32 + nt * 16 + lr;
    const float bias = b2[col];
    const int cp = col >> 1;               // column-pair index (shared with lane^1)
#pragma unroll
    for (int mt = 0; mt < 4; ++mt) {
      const unsigned int fx0 = (unsigned int)(softplus_f(acc2[mt][nt][0] + bias) * FXS);
      const unsigned int fx1 = (unsigned int)(softplus_f(acc2[mt][nt][1] + bias) * FXS);
      const unsigned int fx2 = (unsigned int)(softplus_f(acc2[mt][nt][2] + bias) * FXS);
      const unsigned int fx3 = (unsigned int)(softplus_f(acc2[mt][nt][3] + bias) * FXS);
      const unsigned int sh0 = (unsigned int)__shfl_xor((int)fx0, 1);
      const unsigned int sh1 = (unsigned int)__shfl_xor((int)fx1, 1);
      const unsigned int sh2 = (unsigned int)__shfl_xor((int)fx2, 1);
      const unsigned int sh3 = (unsigned int)__shfl_xor((int)fx3, 1);
      // even lane: rows {0,1}, lo=self(even col), hi=partner(odd col)
      // odd  lane: rows {2,3}, lo=partner(even col), hi=self(odd col)
      const unsigned long long v0 = parity
          ? (((unsigned long long)fx2 << 32) | sh2)
          : (((unsigned long long)sh0 << 32) | fx0);
      const unsigned long long v1 = parity
          ? (((unsigned long long)fx3 << 32) | sh3)
          : (((unsigned long long)sh1 << 32) | fx1);
      const int rbase = mt * 16 + ((lane >> 4) << 2) + (parity << 1);
      unsigned long long* p0 = aggr64 + (size_t)colS[rbase] * 64 + cp;
      unsigned long long* p1 = aggr64 + (size_t)colS[rbase + 1] * 64 + cp;
      __hip_atomic_fetch_add(p0, v0, __ATOMIC_RELAXED, __HIP_MEMORY_SCOPE_AGENT);
      __hip_atomic_fetch_add(p1, v1, __ATOMIC_RELAXED, __HIP_MEMORY_SCOPE_AGENT);
    }
  }
}

// ---------------- node MLP + residual (decodes fixed-point aggr) ----------------
__global__ __launch_bounds__(256, 4) void node_kernel(
    const float* __restrict__ x, const float* __restrict__ bn,
    const unsigned short* __restrict__ xbf, const unsigned short* __restrict__ wnf,
    const unsigned int* __restrict__ aggrU, float* __restrict__ out) {
  __shared__ __align__(16) unsigned short At[16384];  // 64 x 256 bf16 = 32KB
  const int t = threadIdx.x;
  const int lane = t & 63;
  const int w = t >> 6;
  const int base = blockIdx.x * 64;

  {
    const int r = t >> 2, p = t & 3;
    const int node = base + r;
    const int swz = (r & 7) << 4;
    unsigned short* rowp = At + ((r * 512) >> 1);
    if (node < NN) {
      const u16x8* xr = (const u16x8*)(xbf + (size_t)node * DD + p * 32);
      const uint4* ag = (const uint4*)(aggrU + (size_t)node * DD + p * 32);
#pragma unroll
      for (int i = 0; i < 4; ++i) {
        const int c2 = (p * 32 + i * 8) * 2;
        *(u16x8*)(rowp + ((c2 ^ swz) >> 1)) = xr[i];
        const uint4 q0 = ag[2 * i], q1 = ag[2 * i + 1];
        u16x8 v;
        v[0] = f2bf((float)q0.x * FXI); v[1] = f2bf((float)q0.y * FXI);
        v[2] = f2bf((float)q0.z * FXI); v[3] = f2bf((float)q0.w * FXI);
        v[4] = f2bf((float)q1.x * FXI); v[5] = f2bf((float)q1.y * FXI);
        v[6] = f2bf((float)q1.z * FXI); v[7] = f2bf((float)q1.w * FXI);
        *(u16x8*)(rowp + (((256 + c2) ^ swz) >> 1)) = v;
      }
    } else {
      const u16x8 z = {};
#pragma unroll
      for (int i = 0; i < 4; ++i) {
        const int c2 = (p * 32 + i * 8) * 2;
        *(u16x8*)(rowp + ((c2 ^ swz) >> 1)) = z;
        *(u16x8*)(rowp + (((256 + c2) ^ swz) >> 1)) = z;
      }
    }
  }
  __syncthreads();

  const int lr = lane & 15;
  const int lkb = (lane >> 4) << 4;
  f32x4 acc[4][2] = {};
#pragma unroll
  for (int kt = 0; kt < 8; ++kt) {
    bf16x8 a[4];
#pragma unroll
    for (int mt = 0; mt < 4; ++mt) {
      const int row = mt * 16 + lr;
      const int cb = kt * 64 + lkb;
      a[mt] = __builtin_bit_cast(bf16x8,
              *(const u16x8*)(At + ((row * 512 + (cb ^ ((row & 7) << 4))) >> 1)));
    }
#pragma unroll
    for (int nt = 0; nt < 2; ++nt) {
      const u16x8 bv = *(const u16x8*)(wnf + ((size_t)((kt * 8 + (w * 2 + nt)) * 64 + lane) << 3));
      const bf16x8 b = __builtin_bit_cast(bf16x8, bv);
#pragma unroll
      for (int mt = 0; mt < 4; ++mt)
        acc[mt][nt] = __builtin_amdgcn_mfma_f32_16x16x32_bf16(a[mt], b, acc[mt][nt], 0, 0, 0);
    }
  }

#pragma unroll
  for (int nt = 0; nt < 2; ++nt) {
    const int col = w * 32 + nt * 16 + lr;
    const float bias = bn[col];
#pragma unroll
    for (int mt = 0; mt < 4; ++mt) {
#pragma unroll
      for (int reg = 0; reg < 4; ++reg) {
        const int row = mt * 16 + ((lane >> 4) << 2) + reg;
        const int node = base + row;
        if (node < NN) {
          const size_t o = (size_t)node * DD + col;
          out[o] = softplus_f(acc[mt][nt][reg] + bias) + x[o];
        }
      }
    }
  }
}

// ---------------- launch ----------------
extern "C" void kernel_launch(void* const* d_in, const int* in_sizes, int n_in,
                              void* d_out, int out_size, void* d_ws, size_t ws_size,
                              hipStream_t stream) {
  const float* x = (const float*)d_in[0];
  const int* ei = (const int*)d_in[1];
  const float* eattr = (const float*)d_in[2];
  const float* W1 = (const float*)d_in[3];
  const float* b1 = (const float*)d_in[4];
  const float* W2 = (const float*)d_in[5];
  const float* b2 = (const float*)d_in[6];
  const float* Wn = (const float*)d_in[7];
  const float* bn = (const float*)d_in[8];
  float* out = (float*)d_out;

  char* ws = (char*)d_ws;
  float* aggrF = (float*)(ws);                               // 25,600,000 B (u32 fx / u64 pairs)
  unsigned long long* aggr64 = (unsigned long long*)(ws);
  const unsigned int* aggrU = (const unsigned int*)(ws);
  unsigned short* xbf = (unsigned short*)(ws + 25600000);    // 12,800,000 B
  unsigned short* w1f = (unsigned short*)(ws + 38400000);    //    196,608 B
  unsigned short* w2f = (unsigned short*)(ws + 38596608);    //     65,536 B
  unsigned short* wnf = (unsigned short*)(ws + 38662144);    //     65,536 B  (end 38,727,680)

  prep_kernel<<<9455, 256, 0, stream>>>(x, W1, W2, Wn, xbf, w1f, w2f, wnf, aggrF);
  edge_kernel<<<9375, 256, 0, stream>>>(ei, eattr, b1, b2, xbf, w1f, w2f, aggr64);
  node_kernel<<<782, 256, 0, stream>>>(x, bn, xbf, wnf, aggrU, out);
}